// Round 1
// baseline (407.024 us; speedup 1.0000x reference)
//
#include <hip/hip_runtime.h>

typedef __attribute__((ext_vector_type(8))) __bf16 bf16x8;
typedef __attribute__((ext_vector_type(4))) float f32x4;

__device__ __forceinline__ f32x4 mfma16(bf16x8 a, bf16x8 b, f32x4 c) {
  return __builtin_amdgcn_mfma_f32_16x16x32_bf16(a, b, c, 0, 0, 0);
}

__device__ __forceinline__ void gload_lds16(const void* g, void* l) {
  __builtin_amdgcn_global_load_lds(
      (__attribute__((address_space(1))) void*)(void*)g,
      (__attribute__((address_space(3))) void*)l, 16, 0, 0);
}

// ---------------- cast kernels ----------------

__global__ __launch_bounds__(256) void cast_plain(const float* __restrict__ in,
                                                  __bf16* __restrict__ out) {
  size_t t = (size_t)blockIdx.x * 256 + threadIdx.x;
  const float4* p = (const float4*)(in + t * 8);
  float4 a = p[0], b = p[1];
  bf16x8 v;
  v[0] = (__bf16)a.x; v[1] = (__bf16)a.y; v[2] = (__bf16)a.z; v[3] = (__bf16)a.w;
  v[4] = (__bf16)b.x; v[5] = (__bf16)b.y; v[6] = (__bf16)b.z; v[7] = (__bf16)b.w;
  *(bf16x8*)(out + t * 8) = v;
}

// cat = concat(mem, w) along time axis; out bf16 [4*2048, 1024]
__global__ __launch_bounds__(256) void cast_cat(const float* __restrict__ mem,
                                                const float* __restrict__ w,
                                                __bf16* __restrict__ out) {
  size_t t = (size_t)blockIdx.x * 256 + threadIdx.x;
  size_t o = t * 8;
  int c = (int)(o & 1023);
  int row = (int)(o >> 10);      // b*2048 + tt
  int tt = row & 2047;
  int b = row >> 11;
  const float* src = (tt < 1024)
      ? (mem + ((size_t)(b * 1024 + tt) * 1024 + c))
      : (w + ((size_t)(b * 1024 + (tt - 1024)) * 1024 + c));
  float4 a = ((const float4*)src)[0], d = ((const float4*)src)[1];
  bf16x8 v;
  v[0] = (__bf16)a.x; v[1] = (__bf16)a.y; v[2] = (__bf16)a.z; v[3] = (__bf16)a.w;
  v[4] = (__bf16)d.x; v[5] = (__bf16)d.y; v[6] = (__bf16)d.z; v[7] = (__bf16)d.w;
  *(bf16x8*)(out + o) = v;
}

// ---------------- GEMM: C = A(MxK) * B(NxK)^T ----------------
// MODE 0: bf16 out.  MODE 1: f32 out + residual add.
template <int MODE>
__global__ __launch_bounds__(256, 2) void gemm_bt(const __bf16* __restrict__ A,
                                                  const __bf16* __restrict__ B,
                                                  __bf16* __restrict__ Cb,
                                                  float* __restrict__ Cf,
                                                  const float* __restrict__ Res,
                                                  int M, int N, int K) {
  __shared__ __bf16 As[128 * 32];
  __shared__ __bf16 Bs[128 * 32];
  const int tid = threadIdx.x;
  const int wid = tid >> 6, lane = tid & 63;
  const int l15 = lane & 15, lhi = lane >> 4;
  const int wr = wid >> 1, wc = wid & 1;
  const size_t arow0 = (size_t)blockIdx.y * 128;
  const size_t brow0 = (size_t)blockIdx.x * 128;

  f32x4 acc[4][4] = {};

  const int c0 = tid, c1 = tid + 256;
  const int r0 = c0 >> 2, o0 = (c0 & 3) * 8;
  const int r1 = c1 >> 2, o1 = (c1 & 3) * 8;
  const __bf16* ga0 = A + (arow0 + r0) * K + o0;
  const __bf16* ga1 = A + (arow0 + r1) * K + o1;
  const __bf16* gb0 = B + (brow0 + r0) * K + o0;
  const __bf16* gb1 = B + (brow0 + r1) * K + o1;
  __bf16* la0 = As + wid * 512;
  __bf16* la1 = As + 2048 + wid * 512;
  __bf16* lb0 = Bs + wid * 512;
  __bf16* lb1 = Bs + 2048 + wid * 512;

  for (int k0 = 0; k0 < K; k0 += 32) {
    gload_lds16(ga0 + k0, la0);
    gload_lds16(ga1 + k0, la1);
    gload_lds16(gb0 + k0, lb0);
    gload_lds16(gb1 + k0, lb1);
    __syncthreads();
    bf16x8 af[4], bf[4];
#pragma unroll
    for (int m = 0; m < 4; ++m)
      af[m] = *(const bf16x8*)(As + (wr * 64 + m * 16 + l15) * 32 + lhi * 8);
#pragma unroll
    for (int n = 0; n < 4; ++n)
      bf[n] = *(const bf16x8*)(Bs + (wc * 64 + n * 16 + l15) * 32 + lhi * 8);
#pragma unroll
    for (int m = 0; m < 4; ++m)
#pragma unroll
      for (int n = 0; n < 4; ++n)
        acc[m][n] = mfma16(af[m], bf[n], acc[m][n]);
    __syncthreads();
  }

#pragma unroll
  for (int m = 0; m < 4; ++m)
#pragma unroll
    for (int n = 0; n < 4; ++n) {
      size_t row = arow0 + wr * 64 + m * 16 + lhi * 4;
      size_t col = brow0 + wc * 64 + n * 16 + l15;
#pragma unroll
      for (int j = 0; j < 4; ++j) {
        size_t idx = (row + j) * (size_t)N + col;
        float v = acc[m][n][j];
        if (MODE == 0) Cb[idx] = (__bf16)v;
        else Cf[idx] = v + Res[idx];
      }
    }
}

// ---------------- attention ----------------
// heads bf16 [4][2048][3072] (q | k | v sections of 1024 each)
// rk bf16 [2048][1024]; vec bf16 [4][1024][1024]
__global__ __launch_bounds__(256, 2) void attn_kernel(
    const __bf16* __restrict__ heads, const __bf16* __restrict__ rk,
    const float* __restrict__ r_w_bias, const float* __restrict__ r_r_bias,
    __bf16* __restrict__ vec) {
  const int bq = blockIdx.x, h = blockIdx.y, b = blockIdx.z;
  const int tid = threadIdx.x;
  const int wid = tid >> 6, lane = tid & 63;
  const int l15 = lane & 15, lhi = lane >> 4;
  const int i0 = bq * 64 + wid * 16;

  __shared__ __bf16 Vs[64][74];       // V^T tile: [d][j]
  __shared__ float band[4][16][82];   // per-wave BD band (width 80 used)
  __shared__ __bf16 Ps[4][16][72];    // per-wave P tile [i][j]

  // Q fragments with biases
  bf16x8 qw[2], qr[2];
  {
    const __bf16* qp = heads + ((size_t)(b * 2048 + 1024 + i0 + l15)) * 3072 + h * 64;
#pragma unroll
    for (int kk = 0; kk < 2; ++kk) {
      bf16x8 q = *(const bf16x8*)(qp + kk * 32 + lhi * 8);
      bf16x8 aw, ar;
#pragma unroll
      for (int e = 0; e < 8; ++e) {
        float qf = (float)q[e];
        float bw = r_w_bias[h * 64 + kk * 32 + lhi * 8 + e];
        float br = r_r_bias[h * 64 + kk * 32 + lhi * 8 + e];
        aw[e] = (__bf16)(qf + bw);
        ar[e] = (__bf16)(qf + br);
      }
      qw[kk] = aw;
      qr[kk] = ar;
    }
  }

  float m_run[4], l_run[4], corr[4];
  f32x4 accv[4];
#pragma unroll
  for (int r2 = 0; r2 < 4; ++r2) { m_run[r2] = -1e30f; l_run[r2] = 0.f; }
#pragma unroll
  for (int dt = 0; dt < 4; ++dt) accv[dt] = (f32x4){0.f, 0.f, 0.f, 0.f};

  const int jmax = min(2048, bq * 64 + 1088);
  for (int j0 = 0; j0 < jmax; j0 += 64) {
    __syncthreads();
    {  // stage V^T cooperatively
      int j = tid >> 2, d0 = (tid & 3) * 16;
      const __bf16* vp =
          heads + ((size_t)(b * 2048 + j0 + j)) * 3072 + 2048 + h * 64 + d0;
      bf16x8 v0 = *(const bf16x8*)vp;
      bf16x8 v1 = *(const bf16x8*)(vp + 8);
#pragma unroll
      for (int e = 0; e < 8; ++e) {
        Vs[d0 + e][j] = v0[e];
        Vs[d0 + 8 + e][j] = v1[e];
      }
    }
    __syncthreads();

    // AC
    f32x4 s[4];
#pragma unroll
    for (int jt = 0; jt < 4; ++jt) {
      const __bf16* kp = heads +
          ((size_t)(b * 2048 + j0 + jt * 16 + l15)) * 3072 + 1024 + h * 64 + lhi * 8;
      bf16x8 kf0 = *(const bf16x8*)kp;
      bf16x8 kf1 = *(const bf16x8*)(kp + 32);
      f32x4 t = {0.f, 0.f, 0.f, 0.f};
      t = mfma16(qw[0], kf0, t);
      t = mfma16(qw[1], kf1, t);
      s[jt] = t;
    }
    // BD band: band[c] = qr . rk[jjbase + c], c in [0,80)
    const int jjbase = j0 + 1008 - i0;
#pragma unroll
    for (int ct = 0; ct < 5; ++ct) {
      int jj = jjbase + ct * 16 + l15;
      jj = jj < 0 ? 0 : (jj > 2047 ? 2047 : jj);
      const __bf16* rp = rk + (size_t)jj * 1024 + h * 64 + lhi * 8;
      bf16x8 rf0 = *(const bf16x8*)rp;
      bf16x8 rf1 = *(const bf16x8*)(rp + 32);
      f32x4 t = {0.f, 0.f, 0.f, 0.f};
      t = mfma16(qr[0], rf0, t);
      t = mfma16(qr[1], rf1, t);
#pragma unroll
      for (int e = 0; e < 4; ++e) band[wid][lhi * 4 + e][ct * 16 + l15] = t[e];
    }
    // assemble S = (AC + shifted BD)*scale with mask
#pragma unroll
    for (int jt = 0; jt < 4; ++jt) {
#pragma unroll
      for (int r2 = 0; r2 < 4; ++r2) {
        int rloc = lhi * 4 + r2;
        int jc = jt * 16 + l15;
        float v = (s[jt][r2] + band[wid][rloc][jc + 15 - rloc]) * 0.125f;
        if (j0 + jc > i0 + rloc + 1024) v = -1e30f;
        s[jt][r2] = v;
      }
    }
    // online softmax
#pragma unroll
    for (int r2 = 0; r2 < 4; ++r2) {
      float mx = fmaxf(fmaxf(s[0][r2], s[1][r2]), fmaxf(s[2][r2], s[3][r2]));
#pragma unroll
      for (int off = 1; off < 16; off <<= 1) mx = fmaxf(mx, __shfl_xor(mx, off, 64));
      float mn = fmaxf(m_run[r2], mx);
      float c = __expf(m_run[r2] - mn);
      float rs = 0.f;
#pragma unroll
      for (int jt = 0; jt < 4; ++jt) {
        float p = __expf(s[jt][r2] - mn);
        s[jt][r2] = p;
        rs += p;
      }
#pragma unroll
      for (int off = 1; off < 16; off <<= 1) rs += __shfl_xor(rs, off, 64);
      m_run[r2] = mn;
      l_run[r2] = l_run[r2] * c + rs;
      corr[r2] = c;
    }
#pragma unroll
    for (int dt = 0; dt < 4; ++dt)
#pragma unroll
      for (int r2 = 0; r2 < 4; ++r2) accv[dt][r2] *= corr[r2];
    // P -> LDS -> A fragments
#pragma unroll
    for (int jt = 0; jt < 4; ++jt)
#pragma unroll
      for (int r2 = 0; r2 < 4; ++r2)
        Ps[wid][lhi * 4 + r2][jt * 16 + l15] = (__bf16)s[jt][r2];
    bf16x8 ap0 = *(const bf16x8*)&Ps[wid][l15][lhi * 8];
    bf16x8 ap1 = *(const bf16x8*)&Ps[wid][l15][32 + lhi * 8];
#pragma unroll
    for (int dt = 0; dt < 4; ++dt) {
      bf16x8 bv0 = *(const bf16x8*)&Vs[dt * 16 + l15][lhi * 8];
      bf16x8 bv1 = *(const bf16x8*)&Vs[dt * 16 + l15][32 + lhi * 8];
      accv[dt] = mfma16(ap0, bv0, accv[dt]);
      accv[dt] = mfma16(ap1, bv1, accv[dt]);
    }
  }

#pragma unroll
  for (int dt = 0; dt < 4; ++dt)
#pragma unroll
    for (int r2 = 0; r2 < 4; ++r2) {
      float v = accv[dt][r2] / l_run[r2];
      vec[((size_t)(b * 1024 + i0 + lhi * 4 + r2)) * 1024 + h * 64 + dt * 16 + l15] =
          (__bf16)v;
    }
}

// ---------------- layernorm ----------------
__global__ __launch_bounds__(256) void ln_kernel(const float* __restrict__ pre,
                                                 const float* __restrict__ gamma,
                                                 const float* __restrict__ beta,
                                                 float* __restrict__ out) {
  const int row = blockIdx.x;
  const int tid = threadIdx.x;
  const float4 v = ((const float4*)(pre + (size_t)row * 1024))[tid];
  float s = v.x + v.y + v.z + v.w;
  float s2 = v.x * v.x + v.y * v.y + v.z * v.z + v.w * v.w;
#pragma unroll
  for (int off = 1; off < 64; off <<= 1) {
    s += __shfl_xor(s, off, 64);
    s2 += __shfl_xor(s2, off, 64);
  }
  __shared__ float red[8];
  const int wid = tid >> 6;
  if ((tid & 63) == 0) { red[wid * 2] = s; red[wid * 2 + 1] = s2; }
  __syncthreads();
  s = red[0] + red[2] + red[4] + red[6];
  s2 = red[1] + red[3] + red[5] + red[7];
  float mu = s * (1.0f / 1024.0f);
  float var = s2 * (1.0f / 1024.0f) - mu * mu;
  float rstd = rsqrtf(var + 1e-5f);
  float4 g = ((const float4*)gamma)[tid];
  float4 be = ((const float4*)beta)[tid];
  float4 o;
  o.x = (v.x - mu) * rstd * g.x + be.x;
  o.y = (v.y - mu) * rstd * g.y + be.y;
  o.z = (v.z - mu) * rstd * g.z + be.z;
  o.w = (v.w - mu) * rstd * g.w + be.w;
  ((float4*)(out + (size_t)row * 1024))[tid] = o;
}

// ---------------- launcher ----------------
extern "C" void kernel_launch(void* const* d_in, const int* in_sizes, int n_in,
                              void* d_out, int out_size, void* d_ws, size_t ws_size,
                              hipStream_t stream) {
  const float* w = (const float*)d_in[0];        // [4,1024,1024]
  const float* r = (const float*)d_in[1];        // [1,2048,1024]
  const float* mem = (const float*)d_in[2];      // [4,1024,1024]
  const float* qkv_w = (const float*)d_in[4];    // [3072,1024]
  const float* r_w = (const float*)d_in[5];      // [1024,1024]
  const float* o_w = (const float*)d_in[6];      // [1024,1024]
  const float* r_r_bias = (const float*)d_in[7]; // [16,64]
  const float* r_w_bias = (const float*)d_in[8]; // [16,64]
  const float* gamma = (const float*)d_in[9];
  const float* beta = (const float*)d_in[10];
  float* out = (float*)d_out;

  char* ws = (char*)d_ws;
  const size_t MB = 1024 * 1024;
  __bf16* catB = (__bf16*)(ws + 0);        // 16 MB  [8192][1024]
  float* pre = (float*)(ws + 0);           // 16 MB  [4096][1024] (reuses catB region after GEMM1)
  __bf16* qkvwB = (__bf16*)(ws + 16 * MB); // 6 MB   [3072][1024]
  __bf16* rB = (__bf16*)(ws + 22 * MB);    // 4 MB   [2048][1024]
  __bf16* rwB = (__bf16*)(ws + 26 * MB);   // 2 MB   [1024][1024]
  __bf16* owB = (__bf16*)(ws + 28 * MB);   // 2 MB   [1024][1024]
  __bf16* headsB = (__bf16*)(ws + 30 * MB);// 48 MB  [8192][3072]
  __bf16* rkB = (__bf16*)(ws + 78 * MB);   // 4 MB   [2048][1024]
  __bf16* vecB = (__bf16*)(ws + 82 * MB);  // 8 MB   [4096][1024]

  // casts
  cast_cat<<<4096, 256, 0, stream>>>(mem, w, catB);
  cast_plain<<<1536, 256, 0, stream>>>(qkv_w, qkvwB);
  cast_plain<<<1024, 256, 0, stream>>>(r, rB);
  cast_plain<<<512, 256, 0, stream>>>(r_w, rwB);
  cast_plain<<<512, 256, 0, stream>>>(o_w, owB);

  // heads = cat @ qkv_w^T
  gemm_bt<0><<<dim3(24, 64), 256, 0, stream>>>(catB, qkvwB, headsB, nullptr, nullptr,
                                               8192, 3072, 1024);
  // rk = r @ r_w^T
  gemm_bt<0><<<dim3(8, 16), 256, 0, stream>>>(rB, rwB, rkB, nullptr, nullptr,
                                              2048, 1024, 1024);
  // attention
  attn_kernel<<<dim3(16, 16, 4), 256, 0, stream>>>(headsB, rkB, r_w_bias, r_r_bias,
                                                   vecB);
  // pre = vec @ o_w^T + w
  gemm_bt<1><<<dim3(8, 32), 256, 0, stream>>>(vecB, owB, nullptr, pre, w,
                                              4096, 1024, 1024);
  // out = LN(pre)
  ln_kernel<<<4096, 256, 0, stream>>>(pre, gamma, beta, out);
}

// Round 2
// 355.945 us; speedup vs baseline: 1.1435x; 1.1435x over previous
//
#include <hip/hip_runtime.h>

typedef __attribute__((ext_vector_type(8))) __bf16 bf16x8;
typedef __attribute__((ext_vector_type(4))) __bf16 bf16x4;
typedef __attribute__((ext_vector_type(4))) float f32x4;

__device__ __forceinline__ f32x4 mfma16(bf16x8 a, bf16x8 b, f32x4 c) {
  return __builtin_amdgcn_mfma_f32_16x16x32_bf16(a, b, c, 0, 0, 0);
}

__device__ __forceinline__ void gload_lds16(const void* g, void* l) {
  __builtin_amdgcn_global_load_lds(
      (__attribute__((address_space(1))) void*)(void*)g,
      (__attribute__((address_space(3))) void*)l, 16, 0, 0);
}

// read swizzled [64-row][64-elem] LDS tile: logical chunk lc (0..7) of row
__device__ __forceinline__ bf16x8 ldsfrag(const __bf16* base, int row, int lc) {
  return *(const bf16x8*)(base + row * 64 + ((lc ^ (row & 7)) << 3));
}

// ---------------- cast kernels ----------------

__global__ __launch_bounds__(256) void cast_plain(const float* __restrict__ in,
                                                  __bf16* __restrict__ out) {
  size_t t = (size_t)blockIdx.x * 256 + threadIdx.x;
  const float4* p = (const float4*)(in + t * 8);
  float4 a = p[0], b = p[1];
  bf16x8 v;
  v[0] = (__bf16)a.x; v[1] = (__bf16)a.y; v[2] = (__bf16)a.z; v[3] = (__bf16)a.w;
  v[4] = (__bf16)b.x; v[5] = (__bf16)b.y; v[6] = (__bf16)b.z; v[7] = (__bf16)b.w;
  *(bf16x8*)(out + t * 8) = v;
}

__global__ __launch_bounds__(256) void cast_cat(const float* __restrict__ mem,
                                                const float* __restrict__ w,
                                                __bf16* __restrict__ out) {
  size_t t = (size_t)blockIdx.x * 256 + threadIdx.x;
  size_t o = t * 8;
  int c = (int)(o & 1023);
  int row = (int)(o >> 10);
  int tt = row & 2047;
  int b = row >> 11;
  const float* src = (tt < 1024)
      ? (mem + ((size_t)(b * 1024 + tt) * 1024 + c))
      : (w + ((size_t)(b * 1024 + (tt - 1024)) * 1024 + c));
  float4 a = ((const float4*)src)[0], d = ((const float4*)src)[1];
  bf16x8 v;
  v[0] = (__bf16)a.x; v[1] = (__bf16)a.y; v[2] = (__bf16)a.z; v[3] = (__bf16)a.w;
  v[4] = (__bf16)d.x; v[5] = (__bf16)d.y; v[6] = (__bf16)d.z; v[7] = (__bf16)d.w;
  *(bf16x8*)(out + o) = v;
}

// ---------------- GEMM: C = A(MxK) * B(NxK)^T ----------------
template <int MODE>
__global__ __launch_bounds__(256, 2) void gemm_bt(const __bf16* __restrict__ A,
                                                  const __bf16* __restrict__ B,
                                                  __bf16* __restrict__ Cb,
                                                  float* __restrict__ Cf,
                                                  const float* __restrict__ Res,
                                                  int M, int N, int K) {
  __shared__ __bf16 As[128 * 32];
  __shared__ __bf16 Bs[128 * 32];
  const int tid = threadIdx.x;
  const int wid = tid >> 6, lane = tid & 63;
  const int l15 = lane & 15, lhi = lane >> 4;
  const int wr = wid >> 1, wc = wid & 1;
  const size_t arow0 = (size_t)blockIdx.y * 128;
  const size_t brow0 = (size_t)blockIdx.x * 128;

  f32x4 acc[4][4] = {};

  const int c0 = tid, c1 = tid + 256;
  const int r0 = c0 >> 2, o0 = (c0 & 3) * 8;
  const int r1 = c1 >> 2, o1 = (c1 & 3) * 8;
  const __bf16* ga0 = A + (arow0 + r0) * K + o0;
  const __bf16* ga1 = A + (arow0 + r1) * K + o1;
  const __bf16* gb0 = B + (brow0 + r0) * K + o0;
  const __bf16* gb1 = B + (brow0 + r1) * K + o1;
  __bf16* la0 = As + wid * 512;
  __bf16* la1 = As + 2048 + wid * 512;
  __bf16* lb0 = Bs + wid * 512;
  __bf16* lb1 = Bs + 2048 + wid * 512;

  for (int k0 = 0; k0 < K; k0 += 32) {
    gload_lds16(ga0 + k0, la0);
    gload_lds16(ga1 + k0, la1);
    gload_lds16(gb0 + k0, lb0);
    gload_lds16(gb1 + k0, lb1);
    __syncthreads();
    bf16x8 af[4], bf[4];
#pragma unroll
    for (int m = 0; m < 4; ++m)
      af[m] = *(const bf16x8*)(As + (wr * 64 + m * 16 + l15) * 32 + lhi * 8);
#pragma unroll
    for (int n = 0; n < 4; ++n)
      bf[n] = *(const bf16x8*)(Bs + (wc * 64 + n * 16 + l15) * 32 + lhi * 8);
#pragma unroll
    for (int m = 0; m < 4; ++m)
#pragma unroll
      for (int n = 0; n < 4; ++n)
        acc[m][n] = mfma16(af[m], bf[n], acc[m][n]);
    __syncthreads();
  }

#pragma unroll
  for (int m = 0; m < 4; ++m)
#pragma unroll
    for (int n = 0; n < 4; ++n) {
      size_t row = arow0 + wr * 64 + m * 16 + lhi * 4;
      size_t col = brow0 + wc * 64 + n * 16 + l15;
#pragma unroll
      for (int j = 0; j < 4; ++j) {
        size_t idx = (row + j) * (size_t)N + col;
        float v = acc[m][n][j];
        if (MODE == 0) Cb[idx] = (__bf16)v;
        else Cf[idx] = v + Res[idx];
      }
    }
}

// ---------------- V transpose: vT[b][h][d][j] ----------------
__global__ __launch_bounds__(256) void vtrans_kernel(const __bf16* __restrict__ heads,
                                                     __bf16* __restrict__ vT) {
  __shared__ __bf16 T[64][66];
  const int j0 = blockIdx.x * 64;
  const int h = blockIdx.y, b = blockIdx.z;
  const int tid = threadIdx.x;
  {
    int jj = tid >> 2, dq = tid & 3;
    const __bf16* src = heads + ((size_t)(b * 2048 + j0 + jj)) * 3072 + 2048 + h * 64 + dq * 16;
    bf16x8 a = *(const bf16x8*)src;
    bf16x8 c = *(const bf16x8*)(src + 8);
#pragma unroll
    for (int e = 0; e < 8; ++e) { T[jj][dq * 16 + e] = a[e]; T[jj][dq * 16 + 8 + e] = c[e]; }
  }
  __syncthreads();
  {
    int d = tid >> 2, jq = tid & 3;
    bf16x8 o0, o1;
#pragma unroll
    for (int e = 0; e < 8; ++e) { o0[e] = T[jq * 16 + e][d]; o1[e] = T[jq * 16 + 8 + e][d]; }
    __bf16* dst = vT + ((size_t)((b * 16 + h) * 64 + d)) * 2048 + j0 + jq * 16;
    *(bf16x8*)dst = o0;
    *(bf16x8*)(dst + 8) = o1;
  }
}

// ---------------- bias-dot precomputes ----------------
// ackb[b][h][j] = sum_d r_w_bias[h][d] * K[b][j][h][d]
__global__ __launch_bounds__(256) void ackb_kernel(const __bf16* __restrict__ heads,
                                                   const float* __restrict__ r_w_bias,
                                                   float* __restrict__ ackb) {
  int gid = blockIdx.x * 256 + threadIdx.x;  // 131072
  int j = gid & 2047, bh = gid >> 11, b = bh >> 4, h = bh & 15;
  const __bf16* kp = heads + ((size_t)(b * 2048 + j)) * 3072 + 1024 + h * 64;
  const float* bw = r_w_bias + h * 64;
  float s = 0.f;
#pragma unroll
  for (int o = 0; o < 8; ++o) {
    bf16x8 kv = *(const bf16x8*)(kp + o * 8);
#pragma unroll
    for (int e = 0; e < 8; ++e) s += (float)kv[e] * bw[o * 8 + e];
  }
  ackb[(size_t)bh * 2048 + j] = s;
}

// brk[h][t] = sum_d r_r_bias[h][d] * rk[t][h][d]
__global__ __launch_bounds__(256) void brk_kernel(const __bf16* __restrict__ rk,
                                                  const float* __restrict__ r_r_bias,
                                                  float* __restrict__ brk) {
  int gid = blockIdx.x * 256 + threadIdx.x;  // 32768
  int t = gid & 2047, h = gid >> 11;
  const __bf16* rp = rk + (size_t)t * 1024 + h * 64;
  const float* br = r_r_bias + h * 64;
  float s = 0.f;
#pragma unroll
  for (int o = 0; o < 8; ++o) {
    bf16x8 rv = *(const bf16x8*)(rp + o * 8);
#pragma unroll
    for (int e = 0; e < 8; ++e) s += (float)rv[e] * br[o * 8 + e];
  }
  brk[(size_t)h * 2048 + t] = s;
}

// ---------------- attention ----------------
__global__ __launch_bounds__(256, 2) void attn_kernel(
    const __bf16* __restrict__ heads, const __bf16* __restrict__ rk,
    const __bf16* __restrict__ vT, const float* __restrict__ ackb,
    const float* __restrict__ brk, __bf16* __restrict__ vec) {
  __shared__ __bf16 Ks[64 * 64];
  __shared__ __bf16 Vt[64 * 64];
  __shared__ __bf16 BP[4 * 2 * 16 * 88];  // per (wave,m) band / P union, stride 88

  int lin = blockIdx.x + (blockIdx.y << 3) + (blockIdx.z << 7);  // 0..511
  int nid = ((lin & 7) << 6) + (lin >> 3);                       // XCD-chunked
  const int bq = nid & 7, h = (nid >> 3) & 15, b = nid >> 7;

  const int tid = threadIdx.x;
  const int wid = tid >> 6, lane = tid & 63;
  const int l15 = lane & 15, lhi = lane >> 4;
  const int i0 = bq * 128 + wid * 32;

  // Q fragments (no bias: biases folded into ackb/brk inits)
  bf16x8 q[2][2];
#pragma unroll
  for (int m = 0; m < 2; ++m) {
    const __bf16* qp =
        heads + ((size_t)(b * 2048 + 1024 + i0 + m * 16 + l15)) * 3072 + h * 64 + lhi * 8;
    q[m][0] = *(const bf16x8*)qp;
    q[m][1] = *(const bf16x8*)(qp + 32);
  }

  const float* ackbp = ackb + ((size_t)(b * 16 + h)) * 2048;
  const float* brkp = brk + (size_t)h * 2048;

  float m_run[2][4], l_run[2][4];
  f32x4 accv[2][4];
#pragma unroll
  for (int m = 0; m < 2; ++m)
#pragma unroll
    for (int r2 = 0; r2 < 4; ++r2) {
      m_run[m][r2] = -1e30f;
      l_run[m][r2] = 0.f;
      accv[m][r2] = (f32x4){0.f, 0.f, 0.f, 0.f};
    }

  const int srow = wid * 16 + (lane >> 3);  // staging rows
  const int ch0 = (lane & 7) ^ (srow & 7);
  const int ch1 = (lane & 7) ^ ((srow + 8) & 7);

  const int jmax = min(2048, bq * 128 + 1152);
  for (int j0 = 0; j0 < jmax; j0 += 64) {
    __syncthreads();
    {
      const __bf16* gk0 =
          heads + ((size_t)(b * 2048 + j0 + srow)) * 3072 + 1024 + h * 64 + ch0 * 8;
      const __bf16* gk1 =
          heads + ((size_t)(b * 2048 + j0 + srow + 8)) * 3072 + 1024 + h * 64 + ch1 * 8;
      const __bf16* gv0 = vT + ((size_t)((b * 16 + h) * 64 + srow)) * 2048 + j0 + ch0 * 8;
      const __bf16* gv1 = vT + ((size_t)((b * 16 + h) * 64 + srow + 8)) * 2048 + j0 + ch1 * 8;
      gload_lds16(gk0, Ks + (wid * 16) * 64);
      gload_lds16(gk1, Ks + (wid * 16 + 8) * 64);
      gload_lds16(gv0, Vt + (wid * 16) * 64);
      gload_lds16(gv1, Vt + (wid * 16 + 8) * 64);
    }
    __syncthreads();
    if (j0 > i0 + 1055) continue;  // fully masked for this wave (barriers matched)

    // ---- AC = q.K^T  (+ackb init) ----
    f32x4 s[2][4];
#pragma unroll
    for (int jt = 0; jt < 4; ++jt) {
      float ai = ackbp[j0 + jt * 16 + l15];
      f32x4 init = {ai, ai, ai, ai};
      bf16x8 k0 = ldsfrag(Ks, jt * 16 + l15, lhi);
      bf16x8 k1 = ldsfrag(Ks, jt * 16 + l15, 4 + lhi);
#pragma unroll
      for (int m = 0; m < 2; ++m)
        s[m][jt] = mfma16(q[m][1], k1, mfma16(q[m][0], k0, init));
    }

    // ---- band^T[c][i] = rk[tbase+c].q_i (+brk init), vectorized b64 writes ----
#pragma unroll
    for (int m = 0; m < 2; ++m) {
      __bf16* bandm = BP + ((wid * 2 + m) * 16) * 88;
      const int tbase = j0 + 1008 - i0 - m * 16;
#pragma unroll
      for (int ct = 0; ct < 5; ++ct) {
        int trow = min(tbase + ct * 16 + l15, 2047);
        const __bf16* rp = rk + (size_t)trow * 1024 + h * 64 + lhi * 8;
        bf16x8 r0 = *(const bf16x8*)rp;
        bf16x8 r1 = *(const bf16x8*)(rp + 32);
        int cb = ct * 16 + lhi * 4;
        f32x4 init = {brkp[min(tbase + cb, 2047)], brkp[min(tbase + cb + 1, 2047)],
                      brkp[min(tbase + cb + 2, 2047)], brkp[min(tbase + cb + 3, 2047)]};
        f32x4 bd = mfma16(r1, q[m][1], mfma16(r0, q[m][0], init));
        bf16x4 bv;
        bv[0] = (__bf16)bd[0]; bv[1] = (__bf16)bd[1];
        bv[2] = (__bf16)bd[2]; bv[3] = (__bf16)bd[3];
        *(bf16x4*)(bandm + l15 * 88 + cb) = bv;  // lane=i(col), regs=4 consecutive c
      }
    }

    // ---- assemble S, online softmax, write P ----
#pragma unroll
    for (int m = 0; m < 2; ++m) {
      __bf16* bandm = BP + ((wid * 2 + m) * 16) * 88;
#pragma unroll
      for (int jt = 0; jt < 4; ++jt) {
#pragma unroll
        for (int r2 = 0; r2 < 4; ++r2) {
          int rloc = lhi * 4 + r2;
          int jc = jt * 16 + l15;
          float v = (s[m][jt][r2] + (float)bandm[rloc * 88 + jc + 15 - rloc]) * 0.125f;
          bool msk = (j0 + jc) > (i0 + m * 16 + rloc + 1024);
          s[m][jt][r2] = msk ? -1e30f : v;
        }
      }
      float corr[4];
#pragma unroll
      for (int r2 = 0; r2 < 4; ++r2) {
        float mx = fmaxf(fmaxf(s[m][0][r2], s[m][1][r2]), fmaxf(s[m][2][r2], s[m][3][r2]));
#pragma unroll
        for (int off = 1; off < 16; off <<= 1) mx = fmaxf(mx, __shfl_xor(mx, off, 64));
        float mn = fmaxf(m_run[m][r2], mx);
        float c = __expf(m_run[m][r2] - mn);
        float rs = 0.f;
#pragma unroll
        for (int jt = 0; jt < 4; ++jt) {
          float p = __expf(s[m][jt][r2] - mn);
          s[m][jt][r2] = p;
          rs += p;
        }
#pragma unroll
        for (int off = 1; off < 16; off <<= 1) rs += __shfl_xor(rs, off, 64);
        m_run[m][r2] = mn;
        l_run[m][r2] = l_run[m][r2] * c + rs;
        corr[r2] = c;
      }
#pragma unroll
      for (int jt = 0; jt < 4; ++jt)
#pragma unroll
        for (int r2 = 0; r2 < 4; ++r2)
          bandm[(lhi * 4 + r2) * 88 + jt * 16 + l15] = (__bf16)s[m][jt][r2];
#pragma unroll
      for (int dt = 0; dt < 4; ++dt)
#pragma unroll
        for (int r2 = 0; r2 < 4; ++r2) accv[m][dt][r2] *= corr[r2];
    }

    // ---- PV ----
    bf16x8 ap[2][2];
#pragma unroll
    for (int m = 0; m < 2; ++m) {
      const __bf16* Pm = BP + ((wid * 2 + m) * 16) * 88;
      ap[m][0] = *(const bf16x8*)(Pm + l15 * 88 + lhi * 8);
      ap[m][1] = *(const bf16x8*)(Pm + l15 * 88 + 32 + lhi * 8);
    }
#pragma unroll
    for (int dt = 0; dt < 4; ++dt) {
      bf16x8 vf0 = ldsfrag(Vt, dt * 16 + l15, lhi);
      bf16x8 vf1 = ldsfrag(Vt, dt * 16 + l15, 4 + lhi);
#pragma unroll
      for (int m = 0; m < 2; ++m)
        accv[m][dt] = mfma16(ap[m][1], vf1, mfma16(ap[m][0], vf0, accv[m][dt]));
    }
  }

#pragma unroll
  for (int m = 0; m < 2; ++m)
#pragma unroll
    for (int dt = 0; dt < 4; ++dt)
#pragma unroll
      for (int r2 = 0; r2 < 4; ++r2) {
        int i = i0 + m * 16 + lhi * 4 + r2;
        float v = accv[m][dt][r2] / l_run[m][r2];
        vec[((size_t)(b * 1024 + i)) * 1024 + h * 64 + dt * 16 + l15] = (__bf16)v;
      }
}

// ---------------- layernorm ----------------
__global__ __launch_bounds__(256) void ln_kernel(const float* __restrict__ pre,
                                                 const float* __restrict__ gamma,
                                                 const float* __restrict__ beta,
                                                 float* __restrict__ out) {
  const int row = blockIdx.x;
  const int tid = threadIdx.x;
  const float4 v = ((const float4*)(pre + (size_t)row * 1024))[tid];
  float s = v.x + v.y + v.z + v.w;
  float s2 = v.x * v.x + v.y * v.y + v.z * v.z + v.w * v.w;
#pragma unroll
  for (int off = 1; off < 64; off <<= 1) {
    s += __shfl_xor(s, off, 64);
    s2 += __shfl_xor(s2, off, 64);
  }
  __shared__ float red[8];
  const int wid = tid >> 6;
  if ((tid & 63) == 0) { red[wid * 2] = s; red[wid * 2 + 1] = s2; }
  __syncthreads();
  s = red[0] + red[2] + red[4] + red[6];
  s2 = red[1] + red[3] + red[5] + red[7];
  float mu = s * (1.0f / 1024.0f);
  float var = s2 * (1.0f / 1024.0f) - mu * mu;
  float rstd = rsqrtf(var + 1e-5f);
  float4 g = ((const float4*)gamma)[tid];
  float4 be = ((const float4*)beta)[tid];
  float4 o;
  o.x = (v.x - mu) * rstd * g.x + be.x;
  o.y = (v.y - mu) * rstd * g.y + be.y;
  o.z = (v.z - mu) * rstd * g.z + be.z;
  o.w = (v.w - mu) * rstd * g.w + be.w;
  ((float4*)(out + (size_t)row * 1024))[tid] = o;
}

// ---------------- launcher ----------------
extern "C" void kernel_launch(void* const* d_in, const int* in_sizes, int n_in,
                              void* d_out, int out_size, void* d_ws, size_t ws_size,
                              hipStream_t stream) {
  const float* w = (const float*)d_in[0];
  const float* r = (const float*)d_in[1];
  const float* mem = (const float*)d_in[2];
  const float* qkv_w = (const float*)d_in[4];
  const float* r_w = (const float*)d_in[5];
  const float* o_w = (const float*)d_in[6];
  const float* r_r_bias = (const float*)d_in[7];
  const float* r_w_bias = (const float*)d_in[8];
  const float* gamma = (const float*)d_in[9];
  const float* beta = (const float*)d_in[10];
  float* out = (float*)d_out;

  char* ws = (char*)d_ws;
  const size_t MB = 1024 * 1024;
  // region [0,16MB): catB -> vT -> pre (sequential lifetimes)
  __bf16* catB = (__bf16*)(ws + 0);
  __bf16* vT = (__bf16*)(ws + 0);
  float* pre = (float*)(ws + 0);
  __bf16* qkvwB = (__bf16*)(ws + 16 * MB);
  __bf16* rB = (__bf16*)(ws + 22 * MB);
  __bf16* rwB = (__bf16*)(ws + 26 * MB);
  __bf16* owB = (__bf16*)(ws + 28 * MB);
  __bf16* headsB = (__bf16*)(ws + 30 * MB);  // 48 MB
  __bf16* rkB = (__bf16*)(ws + 78 * MB);     // 4 MB
  __bf16* vecB = (__bf16*)(ws + 82 * MB);    // 8 MB
  float* ackbF = (float*)(ws + 90 * MB);     // 512 KB
  float* brkF = (float*)(ws + 91 * MB);      // 128 KB

  cast_cat<<<4096, 256, 0, stream>>>(mem, w, catB);
  cast_plain<<<1536, 256, 0, stream>>>(qkv_w, qkvwB);
  cast_plain<<<1024, 256, 0, stream>>>(r, rB);
  cast_plain<<<512, 256, 0, stream>>>(r_w, rwB);
  cast_plain<<<512, 256, 0, stream>>>(o_w, owB);

  gemm_bt<0><<<dim3(24, 64), 256, 0, stream>>>(catB, qkvwB, headsB, nullptr, nullptr,
                                               8192, 3072, 1024);
  gemm_bt<0><<<dim3(8, 16), 256, 0, stream>>>(rB, rwB, rkB, nullptr, nullptr,
                                              2048, 1024, 1024);

  vtrans_kernel<<<dim3(32, 16, 4), 256, 0, stream>>>(headsB, vT);
  ackb_kernel<<<512, 256, 0, stream>>>(headsB, r_w_bias, ackbF);
  brk_kernel<<<128, 256, 0, stream>>>(rkB, r_r_bias, brkF);

  attn_kernel<<<dim3(8, 16, 4), 256, 0, stream>>>(headsB, rkB, vT, ackbF, brkF, vecB);

  gemm_bt<1><<<dim3(8, 32), 256, 0, stream>>>(vecB, owB, nullptr, pre, w,
                                              4096, 1024, 1024);
  ln_kernel<<<4096, 256, 0, stream>>>(pre, gamma, beta, out);
}

// Round 3
// 298.254 us; speedup vs baseline: 1.3647x; 1.1934x over previous
//
#include <hip/hip_runtime.h>

typedef __attribute__((ext_vector_type(8))) __bf16 bf16x8;
typedef __attribute__((ext_vector_type(4))) __bf16 bf16x4;
typedef __attribute__((ext_vector_type(4))) float f32x4;

__device__ __forceinline__ f32x4 mfma16(bf16x8 a, bf16x8 b, f32x4 c) {
  return __builtin_amdgcn_mfma_f32_16x16x32_bf16(a, b, c, 0, 0, 0);
}

__device__ __forceinline__ void gload_lds16(const void* g, void* l) {
  __builtin_amdgcn_global_load_lds(
      (__attribute__((address_space(1))) void*)(void*)g,
      (__attribute__((address_space(3))) void*)l, 16, 0, 0);
}

// read swizzled [row][64-elem] LDS tile: logical chunk lc (0..7) of row
__device__ __forceinline__ bf16x8 ldsfrag(const __bf16* base, int row, int lc) {
  return *(const bf16x8*)(base + row * 64 + ((lc ^ (row & 7)) << 3));
}

// ---------------- cast kernels ----------------

__global__ __launch_bounds__(256) void cast_plain(const float* __restrict__ in,
                                                  __bf16* __restrict__ out) {
  size_t t = (size_t)blockIdx.x * 256 + threadIdx.x;
  const float4* p = (const float4*)(in + t * 8);
  float4 a = p[0], b = p[1];
  bf16x8 v;
  v[0] = (__bf16)a.x; v[1] = (__bf16)a.y; v[2] = (__bf16)a.z; v[3] = (__bf16)a.w;
  v[4] = (__bf16)b.x; v[5] = (__bf16)b.y; v[6] = (__bf16)b.z; v[7] = (__bf16)b.w;
  *(bf16x8*)(out + t * 8) = v;
}

__global__ __launch_bounds__(256) void cast_cat(const float* __restrict__ mem,
                                                const float* __restrict__ w,
                                                __bf16* __restrict__ out) {
  size_t t = (size_t)blockIdx.x * 256 + threadIdx.x;
  size_t o = t * 8;
  int c = (int)(o & 1023);
  int row = (int)(o >> 10);
  int tt = row & 2047;
  int b = row >> 11;
  const float* src = (tt < 1024)
      ? (mem + ((size_t)(b * 1024 + tt) * 1024 + c))
      : (w + ((size_t)(b * 1024 + (tt - 1024)) * 1024 + c));
  float4 a = ((const float4*)src)[0], d = ((const float4*)src)[1];
  bf16x8 v;
  v[0] = (__bf16)a.x; v[1] = (__bf16)a.y; v[2] = (__bf16)a.z; v[3] = (__bf16)a.w;
  v[4] = (__bf16)d.x; v[5] = (__bf16)d.y; v[6] = (__bf16)d.z; v[7] = (__bf16)d.w;
  *(bf16x8*)(out + o) = v;
}

// ---------------- GEMM: C = A(MxK) * B(NxK)^T ----------------
template <int MODE>
__global__ __launch_bounds__(256, 2) void gemm_bt(const __bf16* __restrict__ A,
                                                  const __bf16* __restrict__ B,
                                                  __bf16* __restrict__ Cb,
                                                  float* __restrict__ Cf,
                                                  const float* __restrict__ Res,
                                                  int M, int N, int K) {
  __shared__ __bf16 As[128 * 32];
  __shared__ __bf16 Bs[128 * 32];
  const int tid = threadIdx.x;
  const int wid = tid >> 6, lane = tid & 63;
  const int l15 = lane & 15, lhi = lane >> 4;
  const int wr = wid >> 1, wc = wid & 1;
  const size_t arow0 = (size_t)blockIdx.y * 128;
  const size_t brow0 = (size_t)blockIdx.x * 128;

  f32x4 acc[4][4] = {};

  const int c0 = tid, c1 = tid + 256;
  const int r0 = c0 >> 2, o0 = (c0 & 3) * 8;
  const int r1 = c1 >> 2, o1 = (c1 & 3) * 8;
  const __bf16* ga0 = A + (arow0 + r0) * K + o0;
  const __bf16* ga1 = A + (arow0 + r1) * K + o1;
  const __bf16* gb0 = B + (brow0 + r0) * K + o0;
  const __bf16* gb1 = B + (brow0 + r1) * K + o1;
  __bf16* la0 = As + wid * 512;
  __bf16* la1 = As + 2048 + wid * 512;
  __bf16* lb0 = Bs + wid * 512;
  __bf16* lb1 = Bs + 2048 + wid * 512;

  for (int k0 = 0; k0 < K; k0 += 32) {
    gload_lds16(ga0 + k0, la0);
    gload_lds16(ga1 + k0, la1);
    gload_lds16(gb0 + k0, lb0);
    gload_lds16(gb1 + k0, lb1);
    __syncthreads();
    bf16x8 af[4], bf[4];
#pragma unroll
    for (int m = 0; m < 4; ++m)
      af[m] = *(const bf16x8*)(As + (wr * 64 + m * 16 + l15) * 32 + lhi * 8);
#pragma unroll
    for (int n = 0; n < 4; ++n)
      bf[n] = *(const bf16x8*)(Bs + (wc * 64 + n * 16 + l15) * 32 + lhi * 8);
#pragma unroll
    for (int m = 0; m < 4; ++m)
#pragma unroll
      for (int n = 0; n < 4; ++n)
        acc[m][n] = mfma16(af[m], bf[n], acc[m][n]);
    __syncthreads();
  }

#pragma unroll
  for (int m = 0; m < 4; ++m)
#pragma unroll
    for (int n = 0; n < 4; ++n) {
      size_t row = arow0 + wr * 64 + m * 16 + lhi * 4;
      size_t col = brow0 + wc * 64 + n * 16 + l15;
#pragma unroll
      for (int j = 0; j < 4; ++j) {
        size_t idx = (row + j) * (size_t)N + col;
        float v = acc[m][n][j];
        if (MODE == 0) Cb[idx] = (__bf16)v;
        else Cf[idx] = v + Res[idx];
      }
    }
}

// ---------------- V transpose: vT[b][h][d][j] ----------------
__global__ __launch_bounds__(256) void vtrans_kernel(const __bf16* __restrict__ heads,
                                                     __bf16* __restrict__ vT) {
  __shared__ __bf16 T[64][66];
  const int j0 = blockIdx.x * 64;
  const int h = blockIdx.y, b = blockIdx.z;
  const int tid = threadIdx.x;
  {
    int jj = tid >> 2, dq = tid & 3;
    const __bf16* src = heads + ((size_t)(b * 2048 + j0 + jj)) * 3072 + 2048 + h * 64 + dq * 16;
    bf16x8 a = *(const bf16x8*)src;
    bf16x8 c = *(const bf16x8*)(src + 8);
#pragma unroll
    for (int e = 0; e < 8; ++e) { T[jj][dq * 16 + e] = a[e]; T[jj][dq * 16 + 8 + e] = c[e]; }
  }
  __syncthreads();
  {
    int d = tid >> 2, jq = tid & 3;
    bf16x8 o0, o1;
#pragma unroll
    for (int e = 0; e < 8; ++e) { o0[e] = T[jq * 16 + e][d]; o1[e] = T[jq * 16 + 8 + e][d]; }
    __bf16* dst = vT + ((size_t)((b * 16 + h) * 64 + d)) * 2048 + j0 + jq * 16;
    *(bf16x8*)dst = o0;
    *(bf16x8*)(dst + 8) = o1;
  }
}

// ---------------- bias-dot precomputes (scale 0.125 folded in) ----------------
__global__ __launch_bounds__(256) void ackb_kernel(const __bf16* __restrict__ heads,
                                                   const float* __restrict__ r_w_bias,
                                                   float* __restrict__ ackb) {
  int gid = blockIdx.x * 256 + threadIdx.x;  // 131072
  int j = gid & 2047, bh = gid >> 11, b = bh >> 4, h = bh & 15;
  const __bf16* kp = heads + ((size_t)(b * 2048 + j)) * 3072 + 1024 + h * 64;
  const float* bw = r_w_bias + h * 64;
  float s = 0.f;
#pragma unroll
  for (int o = 0; o < 8; ++o) {
    bf16x8 kv = *(const bf16x8*)(kp + o * 8);
#pragma unroll
    for (int e = 0; e < 8; ++e) s += (float)kv[e] * bw[o * 8 + e];
  }
  ackb[(size_t)bh * 2048 + j] = s * 0.125f;
}

// brk[h][t] padded to 2304 per h (zeros past 2047)
__global__ __launch_bounds__(256) void brk_kernel(const __bf16* __restrict__ rk,
                                                  const float* __restrict__ r_r_bias,
                                                  float* __restrict__ brk) {
  int gid = blockIdx.x * 256 + threadIdx.x;  // 36864
  int t = gid % 2304, h = gid / 2304;
  float s = 0.f;
  if (t < 2048) {
    const __bf16* rp = rk + (size_t)t * 1024 + h * 64;
    const float* br = r_r_bias + h * 64;
#pragma unroll
    for (int o = 0; o < 8; ++o) {
      bf16x8 rv = *(const bf16x8*)(rp + o * 8);
#pragma unroll
      for (int e = 0; e < 8; ++e) s += (float)rv[e] * br[o * 8 + e];
    }
  }
  brk[(size_t)h * 2304 + t] = s * 0.125f;
}

// ---------------- attention (swapped-operand layout, 16 rows/wave) ----------------
__global__ __launch_bounds__(256, 3) void attn_kernel(
    const __bf16* __restrict__ heads, const __bf16* __restrict__ rk,
    const __bf16* __restrict__ vT, const float* __restrict__ ackb,
    const float* __restrict__ brk, __bf16* __restrict__ vec) {
  __shared__ __bf16 Ks[64 * 64];
  __shared__ __bf16 Vt[64 * 64];
  __shared__ __bf16 Ring[128 * 64];   // rk ring buffer, slot = t & 127
  __shared__ __bf16 BPa[4][16 * 88];  // per-wave band/P union

  // decode: XCD = lin&7 -> heads {x, x+8}; seq sweeps bq descending (longest first)
  const int lin = blockIdx.x;
  const int seq = lin >> 3;
  const int bq = 15 - (seq >> 3);
  const int rem = seq & 7;
  const int b = rem >> 1;
  const int h = (lin & 7) + ((rem & 1) << 3);
  const int base = bq << 6;

  const int tid = threadIdx.x;
  const int wid = tid >> 6, lane = tid & 63;
  const int l15 = lane & 15, lhi = lane >> 4;
  const int i0 = base + wid * 16;

  const int srow8 = lane >> 3;
  const int sch = (lane & 7) ^ (srow8 & 7);

  // q fragments, pre-scaled by 0.125 (biases folded into ackb/brk)
  bf16x8 q0, q1;
  {
    const __bf16* qp =
        heads + ((size_t)(b * 2048 + 1024 + i0 + l15)) * 3072 + h * 64 + lhi * 8;
    bf16x8 a = *(const bf16x8*)qp;
    bf16x8 c = *(const bf16x8*)(qp + 32);
#pragma unroll
    for (int e = 0; e < 8; ++e) {
      q0[e] = (__bf16)((float)a[e] * 0.125f);
      q1[e] = (__bf16)((float)c[e] * 0.125f);
    }
  }

  const float* ackbp = ackb + ((size_t)(b * 16 + h)) * 2048;
  const float* brkp = brk + (size_t)h * 2304;
  __bf16* BP = BPa[wid];

  float m_run = -1e30f, l_run = 0.f;
  f32x4 accv[4] = {};

  // prologue: stage rk rows [960-base, 1024-base)
  {
    int r0 = 960 - base + wid * 16 + srow8;
    gload_lds16(rk + (size_t)r0 * 1024 + h * 64 + sch * 8,
                Ring + (((960 - base) + wid * 16) & 127) * 64);
    gload_lds16(rk + (size_t)(r0 + 8) * 1024 + h * 64 + sch * 8,
                Ring + (((960 - base) + wid * 16 + 8) & 127) * 64);
  }

  const int jmaxb = min(2048, base + 1088);
  for (int j0 = 0; j0 < jmaxb; j0 += 64) {
    __syncthreads();  // B0: previous compute done
    {
      const __bf16* kst =
          heads + ((size_t)(b * 2048 + j0 + wid * 16 + srow8)) * 3072 + 1024 + h * 64 + sch * 8;
      gload_lds16(kst, Ks + wid * 16 * 64);
      gload_lds16(kst + (size_t)8 * 3072, Ks + (wid * 16 + 8) * 64);
      const __bf16* vst =
          vT + ((size_t)((b * 16 + h) * 64 + wid * 16 + srow8)) * 2048 + j0 + sch * 8;
      gload_lds16(vst, Vt + wid * 16 * 64);
      gload_lds16(vst + (size_t)8 * 2048, Vt + (wid * 16 + 8) * 64);
      int T0 = j0 + 1024 - base;
      int rr = T0 + wid * 16 + srow8;
      gload_lds16(rk + (size_t)min(rr, 2047) * 1024 + h * 64 + sch * 8,
                  Ring + ((T0 + wid * 16) & 127) * 64);
      gload_lds16(rk + (size_t)min(rr + 8, 2047) * 1024 + h * 64 + sch * 8,
                  Ring + ((T0 + wid * 16 + 8) & 127) * 64);
    }
    __syncthreads();  // B1: staged data ready
    if (j0 >= i0 + 1040) continue;  // fully masked for this wave

    const int tbase = j0 + 1008 - i0;  // >= 0 always

    // ---- band^T[c][i]: mfma(rk, q), rows c, cols i=l15 ----
#pragma unroll
    for (int ct = 0; ct < 5; ++ct) {
      int slot = (tbase + ct * 16 + l15) & 127;
      bf16x8 a0 = ldsfrag(Ring, slot, lhi);
      bf16x8 a1 = ldsfrag(Ring, slot, 4 + lhi);
      f32x4 init = *(const f32x4*)(brkp + tbase + ct * 16 + lhi * 4);
      f32x4 bd = mfma16(a1, q1, mfma16(a0, q0, init));
      bf16x4 bv;
      bv[0] = (__bf16)bd[0]; bv[1] = (__bf16)bd[1];
      bv[2] = (__bf16)bd[2]; bv[3] = (__bf16)bd[3];
      *(bf16x4*)(BP + l15 * 88 + ct * 16 + lhi * 4) = bv;
    }

    // ---- AC^T: mfma(K, q), rows j, cols i=l15, init ackb[j] ----
    f32x4 st[4];
#pragma unroll
    for (int jt = 0; jt < 4; ++jt) {
      bf16x8 k0 = ldsfrag(Ks, jt * 16 + l15, lhi);
      bf16x8 k1 = ldsfrag(Ks, jt * 16 + l15, 4 + lhi);
      f32x4 init = *(const f32x4*)(ackbp + j0 + jt * 16 + lhi * 4);
      st[jt] = mfma16(k1, q1, mfma16(k0, q0, init));
    }

    // ---- assemble S^T (shift = constant per-lane offset) + mask ----
    float sv[4][4];
#pragma unroll
    for (int jt = 0; jt < 4; ++jt)
#pragma unroll
      for (int r2 = 0; r2 < 4; ++r2) {
        int jl = jt * 16 + lhi * 4 + r2;               // j - j0
        float v = st[jt][r2] + (float)BP[l15 * 88 + jl + 15 - l15];
        bool msk = (j0 + jl) > (i0 + l15 + 1024);
        sv[jt][r2] = msk ? -1e30f : v;
      }

    // ---- online softmax: row i = l15 is lane-local ----
    float mx = sv[0][0];
#pragma unroll
    for (int jt = 0; jt < 4; ++jt)
#pragma unroll
      for (int r2 = 0; r2 < 4; ++r2) mx = fmaxf(mx, sv[jt][r2]);
    mx = fmaxf(mx, __shfl_xor(mx, 16, 64));
    mx = fmaxf(mx, __shfl_xor(mx, 32, 64));
    float mn = fmaxf(m_run, mx);
    float corr = __expf(m_run - mn);
    float rs = 0.f;
#pragma unroll
    for (int jt = 0; jt < 4; ++jt)
#pragma unroll
      for (int r2 = 0; r2 < 4; ++r2) {
        float p = __expf(sv[jt][r2] - mn);
        sv[jt][r2] = p;
        rs += p;
      }
    rs += __shfl_xor(rs, 16, 64);
    rs += __shfl_xor(rs, 32, 64);
    m_run = mn;
    l_run = l_run * corr + rs;

    // corr for accv rows (row = lhi*4+r2 lives at lane lhi*4+r2)
    float c4[4];
#pragma unroll
    for (int r2 = 0; r2 < 4; ++r2) c4[r2] = __shfl(corr, lhi * 4 + r2, 64);
#pragma unroll
    for (int dt = 0; dt < 4; ++dt)
#pragma unroll
      for (int r2 = 0; r2 < 4; ++r2) accv[dt][r2] *= c4[r2];

    // ---- P -> LDS (row i = l15), then PV ----
#pragma unroll
    for (int jt = 0; jt < 4; ++jt) {
      bf16x4 pv;
      pv[0] = (__bf16)sv[jt][0]; pv[1] = (__bf16)sv[jt][1];
      pv[2] = (__bf16)sv[jt][2]; pv[3] = (__bf16)sv[jt][3];
      *(bf16x4*)(BP + l15 * 88 + jt * 16 + lhi * 4) = pv;
    }
    bf16x8 ap0 = *(const bf16x8*)(BP + l15 * 88 + lhi * 8);
    bf16x8 ap1 = *(const bf16x8*)(BP + l15 * 88 + 32 + lhi * 8);
#pragma unroll
    for (int dt = 0; dt < 4; ++dt) {
      bf16x8 vf0 = ldsfrag(Vt, dt * 16 + l15, lhi);
      bf16x8 vf1 = ldsfrag(Vt, dt * 16 + l15, 4 + lhi);
      accv[dt] = mfma16(ap1, vf1, mfma16(ap0, vf0, accv[dt]));
    }
  }

  // ---- epilogue: l_run lives at lane = row; fetch via shfl ----
  float inv4[4];
#pragma unroll
  for (int r2 = 0; r2 < 4; ++r2) inv4[r2] = 1.0f / __shfl(l_run, lhi * 4 + r2, 64);
#pragma unroll
  for (int dt = 0; dt < 4; ++dt)
#pragma unroll
    for (int r2 = 0; r2 < 4; ++r2) {
      int i = i0 + lhi * 4 + r2;
      float v = accv[dt][r2] * inv4[r2];
      vec[((size_t)(b * 1024 + i)) * 1024 + h * 64 + dt * 16 + l15] = (__bf16)v;
    }
}

// ---------------- layernorm ----------------
__global__ __launch_bounds__(256) void ln_kernel(const float* __restrict__ pre,
                                                 const float* __restrict__ gamma,
                                                 const float* __restrict__ beta,
                                                 float* __restrict__ out) {
  const int row = blockIdx.x;
  const int tid = threadIdx.x;
  const float4 v = ((const float4*)(pre + (size_t)row * 1024))[tid];
  float s = v.x + v.y + v.z + v.w;
  float s2 = v.x * v.x + v.y * v.y + v.z * v.z + v.w * v.w;
#pragma unroll
  for (int off = 1; off < 64; off <<= 1) {
    s += __shfl_xor(s, off, 64);
    s2 += __shfl_xor(s2, off, 64);
  }
  __shared__ float red[8];
  const int wid = tid >> 6;
  if ((tid & 63) == 0) { red[wid * 2] = s; red[wid * 2 + 1] = s2; }
  __syncthreads();
  s = red[0] + red[2] + red[4] + red[6];
  s2 = red[1] + red[3] + red[5] + red[7];
  float mu = s * (1.0f / 1024.0f);
  float var = s2 * (1.0f / 1024.0f) - mu * mu;
  float rstd = rsqrtf(var + 1e-5f);
  float4 g = ((const float4*)gamma)[tid];
  float4 be = ((const float4*)beta)[tid];
  float4 o;
  o.x = (v.x - mu) * rstd * g.x + be.x;
  o.y = (v.y - mu) * rstd * g.y + be.y;
  o.z = (v.z - mu) * rstd * g.z + be.z;
  o.w = (v.w - mu) * rstd * g.w + be.w;
  ((float4*)(out + (size_t)row * 1024))[tid] = o;
}

// ---------------- launcher ----------------
extern "C" void kernel_launch(void* const* d_in, const int* in_sizes, int n_in,
                              void* d_out, int out_size, void* d_ws, size_t ws_size,
                              hipStream_t stream) {
  const float* w = (const float*)d_in[0];
  const float* r = (const float*)d_in[1];
  const float* mem = (const float*)d_in[2];
  const float* qkv_w = (const float*)d_in[4];
  const float* r_w = (const float*)d_in[5];
  const float* o_w = (const float*)d_in[6];
  const float* r_r_bias = (const float*)d_in[7];
  const float* r_w_bias = (const float*)d_in[8];
  const float* gamma = (const float*)d_in[9];
  const float* beta = (const float*)d_in[10];
  float* out = (float*)d_out;

  char* ws = (char*)d_ws;
  const size_t MB = 1024 * 1024;
  __bf16* catB = (__bf16*)(ws + 0);
  __bf16* vT = (__bf16*)(ws + 0);
  float* pre = (float*)(ws + 0);
  __bf16* qkvwB = (__bf16*)(ws + 16 * MB);
  __bf16* rB = (__bf16*)(ws + 22 * MB);
  __bf16* rwB = (__bf16*)(ws + 26 * MB);
  __bf16* owB = (__bf16*)(ws + 28 * MB);
  __bf16* headsB = (__bf16*)(ws + 30 * MB);  // 48 MB
  __bf16* rkB = (__bf16*)(ws + 78 * MB);     // 4 MB
  __bf16* vecB = (__bf16*)(ws + 82 * MB);    // 8 MB
  float* ackbF = (float*)(ws + 90 * MB);     // 512 KB
  float* brkF = (float*)(ws + 91 * MB);      // 144 KB

  cast_cat<<<4096, 256, 0, stream>>>(mem, w, catB);
  cast_plain<<<1536, 256, 0, stream>>>(qkv_w, qkvwB);
  cast_plain<<<1024, 256, 0, stream>>>(r, rB);
  cast_plain<<<512, 256, 0, stream>>>(r_w, rwB);
  cast_plain<<<512, 256, 0, stream>>>(o_w, owB);

  gemm_bt<0><<<dim3(24, 64), 256, 0, stream>>>(catB, qkvwB, headsB, nullptr, nullptr,
                                               8192, 3072, 1024);
  gemm_bt<0><<<dim3(8, 16), 256, 0, stream>>>(rB, rwB, rkB, nullptr, nullptr,
                                              2048, 1024, 1024);

  vtrans_kernel<<<dim3(32, 16, 4), 256, 0, stream>>>(headsB, vT);
  ackb_kernel<<<512, 256, 0, stream>>>(headsB, r_w_bias, ackbF);
  brk_kernel<<<144, 256, 0, stream>>>(rkB, r_r_bias, brkF);

  attn_kernel<<<1024, 256, 0, stream>>>(headsB, rkB, vT, ackbF, brkF, vecB);

  gemm_bt<1><<<dim3(8, 32), 256, 0, stream>>>(vecB, owB, nullptr, pre, w,
                                              4096, 1024, 1024);
  ln_kernel<<<4096, 256, 0, stream>>>(pre, gamma, beta, out);
}